// Round 6
// baseline (86.520 us; speedup 1.0000x reference)
//
#include <hip/hip_runtime.h>
#include <float.h>

#define CHUNK 2048
#define SUB   2048   // cols per block = full chunk (one resident cohort)
#define MBLK  128    // rows per block = 4 waves x one 32-row strip
#define GRP   256    // B records staged per LDS group (8 KB)
#define NGRP  (SUB / GRP)

typedef __attribute__((ext_vector_type(8)))  short short8;
typedef __attribute__((ext_vector_type(16))) float f32x16;

// ---- bf16 split helpers (RN-even; inputs finite) ----
static __device__ __forceinline__ unsigned short f2bf(float f) {
    unsigned u = __float_as_uint(f);
    return (unsigned short)((u + 0x7FFFu + ((u >> 16) & 1u)) >> 16);
}
static __device__ __forceinline__ float bf2f(unsigned short s) {
    return __uint_as_float(((unsigned)s) << 16);
}

// ---- record formats (verified R5-R17, absmax 0) ----
// A-record (rows side):  [ph(3), pl(3), ph(3), pl(3), sp_hi, sp_lo, 1, 1]
// B-record (cols side):  [uh(3), uh(3), ul(3), ul(3), 1, 1, sq_hi, sq_lo]
// dot_k(A,B) = sp + sq - 2 p.q  (u = -2q, bf16 hi/lo split, exact in f32 MFMA)
// R18: records computed INLINE (pack_kernel dispatch eliminated). Rows side
// always A-format, cols side always B-format — both computable from any
// point, so both dirs use identical code (no operand-role swap needed).
static __device__ __forceinline__ short8 packA_half(float x, float y, float z,
                                                    int half)
{
    unsigned short hx = f2bf(x), hy = f2bf(y), hz = f2bf(z);
    unsigned short lx = f2bf(x - bf2f(hx)), ly = f2bf(y - bf2f(hy)),
                   lz = f2bf(z - bf2f(hz));
    float sp = fmaf(x, x, fmaf(y, y, z * z));
    unsigned short sh = f2bf(sp), sl = f2bf(sp - bf2f(sh));
    short8 a;
    if (half == 0) {
        a[0]=(short)hx; a[1]=(short)hy; a[2]=(short)hz;
        a[3]=(short)lx; a[4]=(short)ly; a[5]=(short)lz;
        a[6]=(short)hx; a[7]=(short)hy;
    } else {
        a[0]=(short)hz; a[1]=(short)lx; a[2]=(short)ly; a[3]=(short)lz;
        a[4]=(short)sh; a[5]=(short)sl; a[6]=(short)0x3F80; a[7]=(short)0x3F80;
    }
    return a;
}

static __device__ __forceinline__ void packB_halves(float x, float y, float z,
                                                    short8& lo, short8& hi)
{
    float ux = -2.0f * x, uy = -2.0f * y, uz = -2.0f * z;
    unsigned short hx = f2bf(ux), hy = f2bf(uy), hz = f2bf(uz);
    unsigned short lx = f2bf(ux - bf2f(hx)), ly = f2bf(uy - bf2f(hy)),
                   lz = f2bf(uz - bf2f(hz));
    float sq = fmaf(x, x, fmaf(y, y, z * z));
    unsigned short sh = f2bf(sq), sl = f2bf(sq - bf2f(sh));
    lo[0]=(short)hx; lo[1]=(short)hy; lo[2]=(short)hz;
    lo[3]=(short)hx; lo[4]=(short)hy; lo[5]=(short)hz;
    lo[6]=(short)lx; lo[7]=(short)ly;
    hi[0]=(short)lz; hi[1]=(short)lx; hi[2]=(short)ly; hi[3]=(short)lz;
    hi[4]=(short)0x3F80; hi[5]=(short)0x3F80; hi[6]=(short)sh; hi[7]=(short)sl;
}

// ---- rowmin tournament across 32 lanes (verified R6-R17, absmax 0) ----
static __device__ __forceinline__ float tourney16(float rm[16], int l31)
{
#pragma unroll
    for (int r = 0; r < 8; ++r) {
        float lo = fminf(rm[r],     __shfl_xor(rm[r],     16));
        float hi = fminf(rm[r + 8], __shfl_xor(rm[r + 8], 16));
        rm[r] = (l31 & 16) ? hi : lo;
    }
#pragma unroll
    for (int r = 0; r < 4; ++r) {
        float lo = fminf(rm[r],     __shfl_xor(rm[r],     8));
        float hi = fminf(rm[r + 4], __shfl_xor(rm[r + 4], 8));
        rm[r] = (l31 & 8) ? hi : lo;
    }
#pragma unroll
    for (int r = 0; r < 2; ++r) {
        float lo = fminf(rm[r],     __shfl_xor(rm[r],     4));
        float hi = fminf(rm[r + 2], __shfl_xor(rm[r + 2], 4));
        rm[r] = (l31 & 4) ? hi : lo;
    }
    {
        float lo = fminf(rm[0], __shfl_xor(rm[0], 2));
        float hi = fminf(rm[1], __shfl_xor(rm[1], 2));
        rm[0] = (l31 & 2) ? hi : lo;
    }
    return fminf(rm[0], __shfl_xor(rm[0], 1));
}

// ---- Pass 1: fused pack + rowmin MFMA + mean partial, one dispatch ----
// R18 vs R17 (82.9; R15 best 81.3):
//  (a) pack_kernel dispatch + gap eliminated (~5 us): A-record computed
//      per-lane from raw floats (one-time); B-records packed per group by
//      the staging threads (reg-load early / pack+ds_write late, T14 split;
//      ~90 VALU cyc/wave/group hidden under the ~320-cyc MFMA cluster).
//  (b) swizzle retained on both LDS sides (write now a plain ds_write, so
//      both sides are in-kernel; same involution u^((u>>3)&7) as R17's
//      proven read; write banks balanced: 8 lanes per bank-group).
// Evidence ledger: LDS-read conflicts NOT critical-path (R17 null); min-VALU
// not critical (R16 +2.1us); single-address fused atomic +20us (R14);
// staged loop beats direct by 5.5us (R13vR14 A/B); LDS/global atomics,
// 2x-work, plain-store pass2, prefetch depth, cohort turnover, TLP trades
// all falsified (R5-R12).
// v_mfma_f32_32x32x16_bf16: A[m=lane&31][k=half*8+j], B[k=half*8+j][n=lane&31],
//   C/D: col=lane&31, row=(reg&3)+8*(reg>>2)+4*half.
__global__ __launch_bounds__(256, 8)
void chamfer_mfma(const float* __restrict__ p1, const float* __restrict__ p2,
                  float* __restrict__ bsum,
                  int n1, int n2, float s2, float s1)
{
    __shared__ alignas(16) unsigned short sb[2][GRP * 16]; // 2 x 8 KB
    __shared__ float wred[4];

    const int dir = blockIdx.z;
    const float* __restrict__ Asrc = dir ? p2 : p1;   // rows side
    const float* __restrict__ Bsrc = dir ? p1 : p2;   // cols side
    const float scale = dir ? s1 : s2;
    const int rows_n = dir ? n2 : n1;
    const int cols_n = dir ? n1 : n2;

    const int tid  = threadIdx.x;
    const int g    = blockIdx.x;          // row group (128 rows, rows side)
    const int yb   = blockIdx.y;          // col chunk (2048 cols, cols side)
    const int bid  = g + gridDim.x * (yb + gridDim.y * dir);
    if (g * MBLK >= rows_n || yb * SUB >= cols_n) {   // uniform per block
        if (tid == 0) bsum[bid] = 0.0f;
        return;
    }

    const int lane = tid & 63;
    const int w    = tid >> 6;
    const int half = lane >> 5;
    const int l31  = lane & 31;

    // A fragment: packed in-register from raw floats (one-time)
    const int rA = g * MBLK + w * 32 + l31;
    const float* ap = Asrc + 3 * (size_t)rA;
    short8 aA = packA_half(ap[0], ap[1], ap[2], half);

    const float* __restrict__ bp = Bsrc + 3 * (size_t)(yb * SUB);

    // LDS swizzle (involution on 16B-unit index, u ^= (u>>3)&7):
    // writer: thread t's record occupies logical units 2t, 2t+1.
    const unsigned wm  = ((unsigned)tid >> 2) & 7u;
    const unsigned wu0 = ((2u * (unsigned)tid)      ^ wm) * 8u;
    const unsigned wu1 = ((2u * (unsigned)tid + 1u) ^ wm) * 8u;
    // reader: logical unit tt*64 + l31*2 + half -> XOR (l31>>2) (tt bits above)
    const unsigned ru  = (((unsigned)(l31 * 2 + half)) ^ ((unsigned)l31 >> 2)) * 8u;

    float rm[16];
#pragma unroll
    for (int r = 0; r < 16; ++r) rm[r] = FLT_MAX;
    const f32x16 z16 = {0,0,0,0, 0,0,0,0, 0,0,0,0, 0,0,0,0};

    // prologue: pack group 0 (thread t -> record t)
    float nx, ny, nz;
    { const float* q = bp + 3 * (size_t)tid; nx = q[0]; ny = q[1]; nz = q[2]; }
    {
        short8 lo, hi;
        packB_halves(nx, ny, nz, lo, hi);
        *(short8*)&sb[0][wu0] = lo;   // ds_write_b128
        *(short8*)&sb[0][wu1] = hi;
    }
    __syncthreads();

    for (int gr = 0; gr < NGRP; ++gr) {
        const int cur = gr & 1;
        if (gr + 1 < NGRP) {     // issue next group's raw loads EARLY
            const float* q = bp + 3 * (size_t)((gr + 1) * GRP + tid);
            nx = q[0]; ny = q[1]; nz = q[2];
        }
        const unsigned short* lb = &sb[cur][ru];
#pragma unroll
        for (int tt = 0; tt < GRP / 32; ++tt) {
            short8 b = *(const short8*)(lb + (size_t)tt * 512);   // ds_read_b128
            f32x16 d = __builtin_amdgcn_mfma_f32_32x32x16_bf16(aA, b, z16, 0, 0, 0);
#pragma unroll
            for (int r = 0; r < 16; ++r) rm[r] = fminf(rm[r], d[r]);
        }
        if (gr + 1 < NGRP) {     // pack + ds_write LATE (latency hidden)
            short8 lo, hi;
            packB_halves(nx, ny, nz, lo, hi);
            *(short8*)&sb[cur ^ 1][wu0] = lo;
            *(short8*)&sb[cur ^ 1][wu1] = hi;
        }
        __syncthreads();         // one barrier per group
    }

    // ---- tournament + block partial sum, one plain store per block ----
    float v = tourney16(rm, l31);
    float c = ((l31 & 1) == 0) ? fmaxf(v, 0.0f) : 0.0f;  // 32 rows/wave counted once
#pragma unroll
    for (int off = 32; off > 0; off >>= 1) c += __shfl_down(c, off);
    if (lane == 0) wred[w] = c;
    __syncthreads();
    if (tid == 0)
        bsum[bid] = (wred[0] + wred[1] + wred[2] + wred[3]) * scale;
}

// ---- Pass 2: reduce per-block partials (n ~ 2048 floats) ----
__global__ __launch_bounds__(256)
void final_reduce(const float* __restrict__ bsum, float* __restrict__ out, int n)
{
    __shared__ float wred[4];
    float s = 0.0f;
    for (int i = threadIdx.x; i < n; i += 256) s += bsum[i];
#pragma unroll
    for (int off = 32; off > 0; off >>= 1) s += __shfl_down(s, off);
    const int lane = threadIdx.x & 63, w = threadIdx.x >> 6;
    if (lane == 0) wred[w] = s;
    __syncthreads();
    if (threadIdx.x == 0)
        out[0] = wred[0] + wred[1] + wred[2] + wred[3];
}

// ---- Fallback (ws too small / odd shapes): R1's verified pure-VALU kernel ----
#define FB_RPT  2
#define FB_TILE (256 * FB_RPT)
__global__ __launch_bounds__(256, 2)
void chamfer_valu(const float* __restrict__ p1, const float* __restrict__ p2,
                  int n1, int n2, float* __restrict__ out)
{
    __shared__ float4 q[CHUNK];
    __shared__ float wsum[4];
    const int dir = blockIdx.z;
    const float* __restrict__ src = dir ? p2 : p1;
    const float* __restrict__ ref = dir ? p1 : p2;
    const int nsrc = dir ? n2 : n1;
    const int m    = dir ? n1 : n2;
    const int nchunks = nsrc / CHUNK;
    const int c = blockIdx.y;
    const int tile0 = blockIdx.x * FB_TILE;
    if (c >= nchunks || tile0 >= m) return;
    const float scale = 1.0f / ((float)nchunks * (float)m);
    const float* __restrict__ chunk = src + (size_t)c * CHUNK * 3;
    for (int k = threadIdx.x; k < CHUNK; k += 256) {
        float x = chunk[3*k], y = chunk[3*k+1], z = chunk[3*k+2];
        q[k] = make_float4(x, y, z, fmaf(x, x, fmaf(y, y, z * z)));
    }
    __syncthreads();
    float px[FB_RPT], py[FB_RPT], pz[FB_RPT], sp[FB_RPT], mna[FB_RPT], mnb[FB_RPT];
    bool valid[FB_RPT];
#pragma unroll
    for (int r = 0; r < FB_RPT; ++r) {
        int j = tile0 + threadIdx.x + r * 256;
        valid[r] = (j < m);
        int jj = valid[r] ? j : 0;
        float x = ref[3*jj], y = ref[3*jj+1], z = ref[3*jj+2];
        px[r] = -2.0f*x; py[r] = -2.0f*y; pz[r] = -2.0f*z;
        sp[r] = fmaf(x, x, fmaf(y, y, z * z));
        mna[r] = FLT_MAX; mnb[r] = FLT_MAX;
    }
#pragma unroll 2
    for (int k = 0; k < CHUNK; k += 2) {
        float4 qa = q[k], qb = q[k+1];
#pragma unroll
        for (int r = 0; r < FB_RPT; ++r) {
            mna[r] = fminf(mna[r], fmaf(px[r], qa.x, fmaf(py[r], qa.y, fmaf(pz[r], qa.z, qa.w))));
            mnb[r] = fminf(mnb[r], fmaf(px[r], qb.x, fmaf(py[r], qb.y, fmaf(pz[r], qb.z, qb.w))));
        }
    }
    float sum = 0.0f;
#pragma unroll
    for (int r = 0; r < FB_RPT; ++r)
        if (valid[r]) sum += fmaxf(fminf(mna[r], mnb[r]) + sp[r], 0.0f);
#pragma unroll
    for (int off = 32; off > 0; off >>= 1) sum += __shfl_down(sum, off);
    if ((threadIdx.x & 63) == 0) wsum[threadIdx.x >> 6] = sum;
    __syncthreads();
    if (threadIdx.x == 0)
        atomicAdd(out, (wsum[0]+wsum[1]+wsum[2]+wsum[3]) * scale);
}

extern "C" void kernel_launch(void* const* d_in, const int* in_sizes, int n_in,
                              void* d_out, int out_size, void* d_ws, size_t ws_size,
                              hipStream_t stream)
{
    const float* p1 = (const float*)d_in[0];  // output_pc [N,3]
    const float* p2 = (const float*)d_in[1];  // gt_pc     [M,3]
    float* out = (float*)d_out;
    const int n1 = in_sizes[0] / 3;
    const int n2 = in_sizes[1] / 3;

    const int nc1 = n1 / CHUNK, nc2 = n2 / CHUNK;

    const int gx = max(n1, n2) / MBLK;
    const int gy = max(n1, n2) / SUB;
    const int nblocks = gx * gy * 2;

    float* bsum = (float*)d_ws;                          // nblocks*4 B
    const size_t need = (size_t)nblocks * 4;

    const bool shapes_ok = (n1 % CHUNK == 0) && (n2 % CHUNK == 0) &&
                           (n1 % MBLK == 0) && (n2 % MBLK == 0) &&
                           (n1 % SUB == 0) && (n2 % SUB == 0);

    if (shapes_ok && ws_size >= need) {
        dim3 grid(gx, gy, 2);
        chamfer_mfma<<<grid, 256, 0, stream>>>(
            p1, p2, bsum, n1, n2,
            1.0f / ((float)nc2 * (float)n1), 1.0f / ((float)nc1 * (float)n2));
        final_reduce<<<1, 256, 0, stream>>>(bsum, out, nblocks);
    } else {
        const int t1 = (n2 + FB_TILE - 1) / FB_TILE;
        const int t2 = (n1 + FB_TILE - 1) / FB_TILE;
        dim3 grid(max(t1, t2), max(nc1, nc2), 2);
        chamfer_valu<<<grid, 256, 0, stream>>>(p1, p2, n1, n2, out);
    }
}